// Round 1
// baseline (712.972 us; speedup 1.0000x reference)
//
#include <hip/hip_runtime.h>

#define BB 4096
#define NN 32768
#define LL 12
#define KK 64
#define SS (LL * KK)   // 768 slots

constexpr int TPB    = 256;            // threads per block (4 waves)
constexpr int NBLK   = 2048;           // 8 blocks/CU resident on 256 CUs
constexpr int RPB    = BB / NBLK;      // 2 rows per block
constexpr int F4_ROW = NN / 4;         // 8192 float4 per row
constexpr int F4_THR = F4_ROW / TPB;   // 32 float4 per thread per row
constexpr int UNROLL = 8;              // loads in flight per thread

// workspace layout (bytes)
constexpr size_t WS_MAP  = 0;          // short map[NN]   = 65536 B
constexpr size_t WS_DUP  = 65536;      // short dup[SS]   =  1536 B
constexpr size_t WS_PART = 69632;      // float partials[LL*NBLK] = 98304 B

// Build column->slot map once. map[col] = s+1 for some slot s with
// brother[s]==col (race among duplicates is benign: duplicate slots share the
// same column hence the same gathered value). dup[s] = the winning primary
// slot for s, so every slot reads a slot that IS written during streaming.
__global__ __launch_bounds__(256) void build_map(
    const int* __restrict__ brother,
    short* __restrict__ map,
    short* __restrict__ dup) {
    for (int i = threadIdx.x; i < NN * 2 / 8; i += TPB)
        ((unsigned long long*)map)[i] = 0ULL;
    __syncthreads();
    for (int s = threadIdx.x; s < SS; s += TPB)
        map[brother[s]] = (short)(s + 1);
    __syncthreads();
    for (int s = threadIdx.x; s < SS; s += TPB)
        dup[s] = (short)(map[brother[s]] - 1);
}

// Stream x coalesced (float4), select needed columns via the int16 map
// (coalesced 8B load covering 4 columns, L2-hot), scatter hits into LDS,
// then compute the 12 per-row softmaxes from LDS.
__global__ __launch_bounds__(256) void hsm_stream(
    const float* __restrict__ x,
    const int* __restrict__ brother,
    const int* __restrict__ p_y,
    const short* __restrict__ map,
    const short* __restrict__ dupv,
    float* __restrict__ partials) {

    __shared__ float gath[SS];   // 3 KB -> no occupancy impact

    const int w    = threadIdx.x >> 6;   // wave 0..3
    const int lane = threadIdx.x & 63;

    // hoisted per-wave l-state: wave w owns l = w, w+4, w+8
    int dslot[3], label[3];
    #pragma unroll
    for (int j = 0; j < 3; ++j) {
        const int l   = w + 4 * j;
        const int col = brother[l * KK + lane];
        const int py  = p_y[l];
        label[j] = __ffsll(__ballot(col == py)) - 1;
        dslot[j] = dupv[l * KK + lane];
    }
    float acc[3] = {0.f, 0.f, 0.f};

    const uint2* mp = (const uint2*)map;   // 4 int16 entries per 8B

    for (int r = 0; r < RPB; ++r) {
        const int b = blockIdx.x * RPB + r;
        const float4* __restrict__ xr = (const float4*)(x + (size_t)b * NN);

        #pragma unroll 1
        for (int base = 0; base < F4_THR; base += UNROLL) {
            float4 v[UNROLL];
            uint2  m[UNROLL];
            #pragma unroll
            for (int u = 0; u < UNROLL; ++u) {
                const int fi = (base + u) * TPB + threadIdx.x;  // coalesced
                v[u] = xr[fi];
                m[u] = mp[fi];
            }
            #pragma unroll
            for (int u = 0; u < UNROLL; ++u) {
                if (m[u].x | m[u].y) {                 // any of 4 cols needed (~9%)
                    const int s0 = (int)(short)(m[u].x & 0xffff);
                    const int s1 = (int)(short)(m[u].x >> 16);
                    const int s2 = (int)(short)(m[u].y & 0xffff);
                    const int s3 = (int)(short)(m[u].y >> 16);
                    if (s0 > 0) gath[s0 - 1] = v[u].x;
                    if (s1 > 0) gath[s1 - 1] = v[u].y;
                    if (s2 > 0) gath[s2 - 1] = v[u].z;
                    if (s3 > 0) gath[s3 - 1] = v[u].w;
                }
            }
        }
        __syncthreads();   // gath complete for this row

        #pragma unroll
        for (int j = 0; j < 3; ++j) {
            const float vv = gath[dslot[j]];   // ~consecutive -> conflict-free
            float mx = vv;
            #pragma unroll
            for (int o = 32; o > 0; o >>= 1) mx = fmaxf(mx, __shfl_xor(mx, o));
            float s = __expf(vv - mx);
            #pragma unroll
            for (int o = 32; o > 0; o >>= 1) s += __shfl_xor(s, o);
            acc[j] += mx + __logf(s) - __shfl(vv, label[j]);
        }
        __syncthreads();   // before next row overwrites gath
    }

    if (lane == 0) {
        #pragma unroll
        for (int j = 0; j < 3; ++j)
            partials[(w + 4 * j) * NBLK + blockIdx.x] = acc[j];
    }
}

// Per-l sum over blocks, mean over B, then sum over l (matches reference order).
__global__ __launch_bounds__(256) void hsm_final(
    const float* __restrict__ partials, float* __restrict__ out) {
    const int w = threadIdx.x >> 6, lane = threadIdx.x & 63;
    __shared__ float red[LL];
    #pragma unroll
    for (int j = 0; j < 3; ++j) {
        const int l = w + 4 * j;
        float s = 0.f;
        for (int i = lane; i < NBLK; i += 64) s += partials[l * NBLK + i];
        #pragma unroll
        for (int o = 32; o > 0; o >>= 1) s += __shfl_xor(s, o);
        if (lane == 0) red[l] = s / (float)BB;
    }
    __syncthreads();
    if (threadIdx.x == 0) {
        float t = 0.f;
        #pragma unroll
        for (int i = 0; i < LL; ++i) t += red[i];
        out[0] = t;
    }
}

extern "C" void kernel_launch(void* const* d_in, const int* in_sizes, int n_in,
                              void* d_out, int out_size, void* d_ws, size_t ws_size,
                              hipStream_t stream) {
    const float* x       = (const float*)d_in[0];
    const int*   brother = (const int*)d_in[1];
    const int*   p_y     = (const int*)d_in[2];
    // d_in[3] = y : unused by the reference
    float* out = (float*)d_out;
    char*  ws  = (char*)d_ws;

    short* map      = (short*)(ws + WS_MAP);
    short* dup      = (short*)(ws + WS_DUP);
    float* partials = (float*)(ws + WS_PART);

    build_map<<<1, TPB, 0, stream>>>(brother, map, dup);
    hsm_stream<<<NBLK, TPB, 0, stream>>>(x, brother, p_y, map, dup, partials);
    hsm_final<<<1, 256, 0, stream>>>(partials, out);
}

// Round 2
// 695.754 us; speedup vs baseline: 1.0247x; 1.0247x over previous
//
#include <hip/hip_runtime.h>

#define BB 4096
#define NN 32768
#define LL 12
#define KK 64
#define SS (LL * KK)   // 768 slots

constexpr int TPB   = 256;                    // 4 waves/block
constexpr int NBLK  = 1024;                   // 4 blocks/CU, whole grid resident
constexpr int RPB   = BB / NBLK;              // 4 rows per block
constexpr int F4ROW = NN / 4;                 // 8192 float4 per row
constexpr int BATCH = 8;                      // float4 in flight per thread per buffer
constexpr int NWRD  = NN / 32;                // 1024 bitmap words

// ---- load one batch of 8 coalesced float4 into a register buffer ----
#define LOADB(dst, rowp, bt) do {                                   \
    _Pragma("unroll")                                               \
    for (int u = 0; u < BATCH; ++u)                                 \
        dst[u] = (rowp)[((bt) * BATCH + u) * TPB + tid];            \
} while (0)

// ---- membership-test 8 float4 against the LDS bitmap, scatter hits ----
// rank(col) = pfx[col>>5] + popc(bits below col) ; 4 cols of a float4
// share one 32-col word (one broadcast ds_read_b32 per float4).
#define SCAT(src, bt) do {                                          \
    _Pragma("unroll")                                               \
    for (int u = 0; u < BATCH; ++u) {                               \
        const int fi = ((bt) * BATCH + u) * TPB + tid;              \
        const int wi = fi >> 3;                                     \
        const unsigned wrd = bmp[wi];                               \
        const int sh = (fi & 7) << 2;                               \
        const unsigned nib = (wrd >> sh) & 0xFu;                    \
        if (nib) {                                                  \
            int r = pfx[wi] + __popc(wrd & ((1u << sh) - 1u));      \
            if (nib & 1u) gath[r++] = src[u].x;                     \
            if (nib & 2u) gath[r++] = src[u].y;                     \
            if (nib & 4u) gath[r++] = src[u].z;                     \
            if (nib & 8u) gath[r++] = src[u].w;                     \
        }                                                           \
    }                                                               \
} while (0)

__global__ __launch_bounds__(TPB) void hsm_stream(
    const float* __restrict__ x,
    const int* __restrict__ brother,
    const int* __restrict__ p_y,
    float* __restrict__ partials) {

    __shared__ unsigned bmp[NWRD];   // 4 KB: needed-column bitmap
    __shared__ int      pfx[NWRD];   // 4 KB: exclusive popcount prefix
    __shared__ float    gath[SS];    // 3 KB: compacted needed values (by rank)

    const int tid  = threadIdx.x;
    const int w    = tid >> 6;
    const int lane = tid & 63;

    // issue the first x batch immediately — prologue hides its latency
    const float4* xr = (const float4*)(x + (size_t)(blockIdx.x * RPB) * NN);
    float4 va[BATCH], vb[BATCH];
    LOADB(va, xr, 0);

    // ---- prologue: build bitmap + prefix + per-l state (~1 µs) ----
    #pragma unroll
    for (int i = 0; i < NWRD / TPB; ++i) bmp[i * TPB + tid] = 0u;
    __syncthreads();

    int cols[3], label[3];
    #pragma unroll
    for (int j = 0; j < 3; ++j) {
        const int l = w + 4 * j;                 // wave w owns l = w, w+4, w+8
        cols[j] = brother[l * KK + lane];
        label[j] = __ffsll(__ballot(cols[j] == p_y[l])) - 1;
        const int s = j * TPB + tid;             // also cover all 768 slots
        atomicOr(&bmp[brother[s] >> 5], 1u << (brother[s] & 31));
    }
    __syncthreads();

    if (tid < 64) {                              // wave 0: exclusive prefix scan
        int carry = 0;
        for (int c = 0; c < NWRD / 64; ++c) {
            const int v = __popc(bmp[c * 64 + tid]);
            int inc = v;
            #pragma unroll
            for (int o = 1; o < 64; o <<= 1) {
                const int t = __shfl_up(inc, o);
                if (tid >= o) inc += t;
            }
            pfx[c * 64 + tid] = carry + inc - v;
            carry += __shfl(inc, 63);
        }
    }
    __syncthreads();

    int dslot[3];
    #pragma unroll
    for (int j = 0; j < 3; ++j) {
        const int c = cols[j];
        dslot[j] = pfx[c >> 5] + __popc(bmp[c >> 5] & ((1u << (c & 31)) - 1u));
    }
    float acc[3] = {0.f, 0.f, 0.f};

    // ---- stream RPB rows, 2-buffer ping-pong, softmax per row ----
    for (int r = 0; r < RPB; ++r) {
        LOADB(vb, xr, 1);
        SCAT(va, 0);
        LOADB(va, xr, 2);
        SCAT(vb, 1);
        LOADB(vb, xr, 3);
        SCAT(va, 2);
        const float4* xn = xr + F4ROW;
        if (r + 1 < RPB) LOADB(va, xn, 0);       // next-row prefetch
        SCAT(vb, 3);
        __syncthreads();                          // gath complete for row

        #pragma unroll
        for (int j = 0; j < 3; ++j) {
            const float vv = gath[dslot[j]];
            float mx = vv;
            #pragma unroll
            for (int o = 32; o > 0; o >>= 1) mx = fmaxf(mx, __shfl_xor(mx, o));
            float s = __expf(vv - mx);
            #pragma unroll
            for (int o = 32; o > 0; o >>= 1) s += __shfl_xor(s, o);
            acc[j] += mx + __logf(s) - __shfl(vv, label[j]);
        }
        __syncthreads();                          // before next row overwrites gath
        xr = xn;
    }

    if (lane == 0) {
        #pragma unroll
        for (int j = 0; j < 3; ++j)
            partials[(w + 4 * j) * NBLK + blockIdx.x] = acc[j];
    }
}

// Per-l sum over blocks, mean over B, then sum over l (matches reference order).
__global__ __launch_bounds__(256) void hsm_final(
    const float* __restrict__ partials, float* __restrict__ out) {
    const int w = threadIdx.x >> 6, lane = threadIdx.x & 63;
    __shared__ float red[LL];
    #pragma unroll
    for (int j = 0; j < 3; ++j) {
        const int l = w + 4 * j;
        float s = 0.f;
        for (int i = lane; i < NBLK; i += 64) s += partials[l * NBLK + i];
        #pragma unroll
        for (int o = 32; o > 0; o >>= 1) s += __shfl_xor(s, o);
        if (lane == 0) red[l] = s / (float)BB;
    }
    __syncthreads();
    if (threadIdx.x == 0) {
        float t = 0.f;
        #pragma unroll
        for (int i = 0; i < LL; ++i) t += red[i];
        out[0] = t;
    }
}

extern "C" void kernel_launch(void* const* d_in, const int* in_sizes, int n_in,
                              void* d_out, int out_size, void* d_ws, size_t ws_size,
                              hipStream_t stream) {
    const float* x       = (const float*)d_in[0];
    const int*   brother = (const int*)d_in[1];
    const int*   p_y     = (const int*)d_in[2];
    // d_in[3] = y : unused by the reference
    float* out      = (float*)d_out;
    float* partials = (float*)d_ws;   // LL*NBLK floats = 48 KB << ws_size

    hsm_stream<<<NBLK, TPB, 0, stream>>>(x, brother, p_y, partials);
    hsm_final<<<1, 256, 0, stream>>>(partials, out);
}